// Round 8
// baseline (985.096 us; speedup 1.0000x reference)
//
#include <hip/hip_runtime.h>
#include <hip/hip_bf16.h>

using bf16 = __hip_bfloat16;
typedef __attribute__((ext_vector_type(8))) short bfrag;   // 8 x bf16 (4 VGPR)
typedef __attribute__((ext_vector_type(4))) float ffrag;   // 4 x f32 acc

__device__ __forceinline__ float b2f(bf16 v) { return __bfloat162float(v); }
__device__ __forceinline__ float ldin(const void* p, int i, int isbf) {
    return isbf ? b2f(((const bf16*)p)[i]) : ((const float*)p)[i];
}
// exact-ish two-term bf16 split: v ~= hi + lo, |err| <= 2^-17 |v|
__device__ __forceinline__ void split2(float v, unsigned short& h, unsigned short& l) {
    bf16 hb = __float2bfloat16(v);
    h = __bfloat16_as_ushort(hb);
    l = __bfloat16_as_ushort(__float2bfloat16(v - __bfloat162float(hb)));
}

// ---------------------------------------------------------------------------
// fused prep: every block re-votes dtype locally from cur_x[0:256].
//   bid <  1728 : 3x3 weight pre-split (5 tensors) -> wbase
//   1728..3775  : dep_x NCHW -> NHWC bf16 hi(/lo) planes -> depout
//   3776..4799  : imap = sigmoid(up2_bilinear(in_map)) -> imapF
// block 0 additionally publishes flag + zeroes accum.
// ---------------------------------------------------------------------------
__global__ __launch_bounds__(256)
void prep_all_kernel(const unsigned* __restrict__ cur_x,
                     const void* __restrict__ up_w, const void* __restrict__ c2_w,
                     const void* __restrict__ d1_w, const void* __restrict__ d2_w,
                     const void* __restrict__ d3_w,
                     const void* __restrict__ dep_x, const void* __restrict__ in_map,
                     unsigned short* __restrict__ wbase,
                     unsigned short* __restrict__ depout,
                     float* __restrict__ imapF,
                     float* __restrict__ accum, int* __restrict__ flagout)
{
    __shared__ unsigned short s_h[64][65];
    __shared__ unsigned short s_l[64][65];
    __shared__ int s_flag;
    const int tid = threadIdx.x;
    if (tid < 64) {
        int cnt = 0;
        for (int i = tid; i < 256; i += 64) {
            unsigned e = (cur_x[i] >> 7) & 0xFFu;
            cnt += (e >= 110u && e <= 135u) ? 1 : 0;
        }
#pragma unroll
        for (int off = 32; off > 0; off >>= 1) cnt += __shfl_down(cnt, off, 64);
        if (tid == 0) s_flag = (cnt >= 128) ? 1 : 0;
    }
    __syncthreads();
    const int isbf = s_flag;
    const int bid = blockIdx.x;
    if (bid == 0) {
        if (tid == 0) *flagout = isbf;
        for (int i = tid; i < 896; i += 256) accum[i] = 0.f;
    }
    if (bid < 1728) {
        int o = bid * 256 + tid;
        if (o >= 442368) return;
        const void* w;
        int CIN, NCH, NCOG, lo;
        size_t hoff, losz;
        if (o < 294912) {
            w = up_w; CIN = 128; NCH = 4; NCOG = 16; hoff = 0; lo = o; losz = 294912;
        } else {
            int t = (o - 294912) / 36864;
            lo = (o - 294912) - t * 36864;
            CIN = 64; NCH = 2; NCOG = 4;
            hoff = 589824 + (size_t)t * 73728;
            losz = 36864;
            w = (t == 0) ? c2_w : (t == 1) ? d1_w : (t == 2) ? d2_w : d3_w;
        }
        int j = lo & 7;
        int l = (lo >> 3) & 63;
        int fb = lo >> 9;
        int cg = fb % NCOG;
        int t2 = fb / NCOG;
        int ch = t2 % NCH;
        int tap = t2 / NCH;
        int co = cg * 16 + (l & 15);
        int ci = ch * 32 + (l >> 4) * 8 + j;
        float v = ldin(w, (co * CIN + ci) * 9 + tap, isbf);
        unsigned short h, l2;
        split2(v, h, l2);
        wbase[hoff + lo] = h;
        wbase[hoff + losz + lo] = l2;
    } else if (bid < 3776) {
        int lid = bid - 1728;
        int pb = lid & 63, cb = (lid >> 6) & 1, b = lid >> 7;
        for (int i = tid; i < 4096; i += 256) {
            int ci = i >> 6, pi = i & 63;
            float v = ldin(dep_x, ((b * 128 + cb * 64 + ci) << 12) + (pb << 6) + pi, isbf);
            unsigned short h, l;
            split2(v, h, l);
            s_h[ci][pi] = h;
            if (!isbf) s_l[ci][pi] = l;
        }
        __syncthreads();
        for (int i = tid; i < 4096; i += 256) {
            int ci = i & 63, pi = i >> 6;
            size_t o = ((size_t)(b * 4096 + pb * 64 + pi) << 7) + cb * 64 + ci;
            depout[o] = s_h[ci][pi];
            if (!isbf) depout[8388608 + o] = s_l[ci][pi];
        }
    } else {
        int idx = (bid - 3776) * 256 + tid;   // 262144 total
        int x = idx & 127, y = (idx >> 7) & 127, b = idx >> 14;
        const float s = (float)(63.0 / 127.0);
        float yy = y * s, xx = x * s;
        int y0 = (int)yy, x0 = (int)xx;
        float wy = yy - y0, wx = xx - x0;
        int y1 = min(y0 + 1, 63), x1 = min(x0 + 1, 63);
        int base = b << 12;
        float v00 = ldin(in_map, base + (y0 << 6) + x0, isbf);
        float v01 = ldin(in_map, base + (y0 << 6) + x1, isbf);
        float v10 = ldin(in_map, base + (y1 << 6) + x0, isbf);
        float v11 = ldin(in_map, base + (y1 << 6) + x1, isbf);
        float r0 = v00 * (1.f - wy) + v10 * wy;
        float r1 = v01 * (1.f - wy) + v11 * wy;
        float v = r0 * (1.f - wx) + r1 * wx;
        imapF[idx] = 1.f / (1.f + expf(-v));
    }
}

// ---------------------------------------------------------------------------
// MFMA implicit-GEMM 3x3 conv, pad=1, NHWC f32 output u = conv + bias.
// Block: ROWS x 64 px tile, 64 couts; ROWS*WCO waves = ROWS(px) x WCO(co);
// block dim = 64*ROWS*WCO threads. (R8: ROWS=4,WCO=2 -> 512 thr, 8 waves:
// halo redundancy 2.06x->1.55x, barriers amortized 2x, 24 waves/CU.)
// MODE: 0 = NHWC f32 intermediate; 1 = NCHW flag-dtype external;
//       2 = NHWC bf16 pre-split hi/lo planes.
// DTMODE: -1 runtime; 0/1 compile-time + runtime guard (early exit).
// SWZ: XCD-aware blockIdx.x swizzle (gridDim.x % 8 == 0 required).
// ---------------------------------------------------------------------------
template<int CIN, int COUT, int H, int W, int ROWS, int WCO, int MODE,
         bool SMAP, bool EPI, bool BNIN, bool STATS, int MINW,
         int DTMODE = -1, bool SWZ = false>
__global__ __launch_bounds__(64 * ROWS * WCO, MINW)
void conv3_mfma(const void* __restrict__ in,
                const unsigned short* __restrict__ whi,
                const unsigned short* __restrict__ wlo,
                const void* __restrict__ bias,
                const float* __restrict__ imapF,
                const float* __restrict__ dep,
                const void* __restrict__ betap,
                const float* __restrict__ accum,
                const void* __restrict__ bng, const void* __restrict__ bnbe,
                float* __restrict__ out, const int* __restrict__ flagp,
                float* __restrict__ sacc, int statC)
{
    constexpr int NWAVES = ROWS * WCO;
    constexpr int NTHR = 64 * NWAVES;
    constexpr int NCH  = CIN / 32;
    constexpr int NCOG = COUT / 16;
    constexpr int NCT  = W / 64;
    constexpr int W2h  = 66;
    constexpr int NP   = (ROWS + 2) * W2h;
    constexpr int NPs  = NP + 1;
    constexpr int NE   = 4 * NP;
    constexpr int NIT  = (NE + NTHR - 1) / NTHR;
    constexpr int NF   = (64 / WCO) / 16;
    constexpr int STCO = 64 / WCO;
    constexpr size_t PLANE = (size_t)16 * H * W * CIN;
    constexpr bool NOLO = (DTMODE == 1) && (MODE == 2) && !SMAP;

    if (DTMODE >= 0 && *flagp != DTMODE) return;
    const int isbf = (DTMODE >= 0) ? DTMODE : *flagp;

    __shared__ int4 s_hi[4 * NPs];
    __shared__ int4 s_lo[NOLO ? 1 : 4 * NPs];
    __shared__ float s_ss[BNIN ? 128 : 1];
    __shared__ float s_sm[SMAP ? NP : 1];
    float (*s_st)[NWAVES][STCO] = (float (*)[NWAVES][STCO])s_hi;  // post-loop alias

    const bool uselo = !(isbf && (MODE == 2 || (MODE == 1 && !SMAP)));
    const int tid  = threadIdx.x;
    int bidx = blockIdx.x;
    if (SWZ) bidx = ((bidx & 7) * (gridDim.x >> 3)) + (bidx >> 3);
    const int r0   = (bidx / NCT) * ROWS;     // global row in [0, 16*H)
    const int x0   = (bidx % NCT) * 64;
    const int bimg = r0 / H;
    const int y0im = bimg * H;
    const int coB  = blockIdx.y;

    if (BNIN) {
        if (tid < CIN) {
            const float n = (float)(16 * H * W);
            float S = accum[tid], S2 = accum[CIN + tid];
            float m = S / n;
            float var = fmaxf(S2 / n - m * m, 0.f);
            float scv = ldin(bng, tid, isbf) * rsqrtf(var + 1e-5f);
            s_ss[2 * tid]     = scv;
            s_ss[2 * tid + 1] = ldin(bnbe, tid, isbf) - m * scv;
        }
    }
    if (SMAP) {
        const float* ip = imapF + ((size_t)bimg << 14);   // H=W=128 only
        for (int i = tid; i < NP; i += NTHR) {
            int rr = i / W2h, cc = i - rr * W2h;
            int gy = r0 - 1 + rr, gx = x0 - 1 + cc;
            float sm = 0.f;
            if (gy >= y0im && gy < y0im + H && (unsigned)gx < (unsigned)W) {
                int y = gy - y0im;
                float ctr = ip[(y << 7) + gx];
                float mx = ctr;
#pragma unroll
                for (int dy = -1; dy <= 1; dy++) {
                    int yy = y + dy;
                    if ((unsigned)yy < 128u) {
#pragma unroll
                        for (int dx = -1; dx <= 1; dx++) {
                            int xx = gx + dx;
                            if ((unsigned)xx < 128u) mx = fmaxf(mx, ip[(yy << 7) + xx]);
                        }
                    }
                }
                sm = mx - ctr;
            }
            s_sm[i] = sm;
        }
    }

    const int lane = tid & 63;
    const int wv = tid >> 6;
    const int wpx = wv / WCO, wco = wv % WCO;
    const int lx = lane & 15;
    const int gq = lane >> 4;

    ffrag acc[4][NF];
#pragma unroll
    for (int mf = 0; mf < 4; mf++)
#pragma unroll
        for (int nf = 0; nf < NF; nf++) acc[mf][nf] = ffrag{0.f, 0.f, 0.f, 0.f};

    for (int ch = 0; ch < NCH; ch++) {
        const int c0 = ch * 32;
        __syncthreads();
        // ---------------- stage halo tile (32 channels) ----------------
#pragma unroll
        for (int it = 0; it < NIT; it++) {
            int e = tid + it * NTHR;
            if (e >= NE) break;
            int gg, pixin;
            if (MODE == 1) { gg = e / NP; pixin = e - gg * NP; }
            else           { gg = e & 3;  pixin = e >> 2; }
            int rr = pixin / W2h;
            int cc2 = pixin - rr * W2h;
            int gy = r0 - 1 + rr;
            int gx = x0 - 1 + cc2;
            bool ok = (gy >= y0im) && (gy < y0im + H) && ((unsigned)gx < (unsigned)W);
            if (MODE == 2) {
                int4 hv = make_int4(0, 0, 0, 0), lv = make_int4(0, 0, 0, 0);
                if (ok) {
                    size_t eb = (size_t)(gy * W + gx) * CIN + c0 + 8 * gg;
                    hv = *(const int4*)((const unsigned short*)in + eb);
                    if (!isbf) lv = *(const int4*)((const unsigned short*)in + PLANE + eb);
                }
                s_hi[gg * NPs + pixin] = hv;
                if (!isbf && !NOLO) s_lo[gg * NPs + pixin] = lv;
            } else {
                float v[8];
                if (ok) {
                    if (MODE == 1) {
                        int y = gy - y0im;
                        float sm = SMAP ? s_sm[pixin] : 1.f;
#pragma unroll
                        for (int j = 0; j < 8; j++) {
                            int gi = ((bimg * CIN + c0 + 8 * gg + j) * H + y) * W + gx;
                            v[j] = ldin(in, gi, isbf) * sm;
                        }
                    } else {
                        const float* up = (const float*)in +
                            ((size_t)gy * W + gx) * CIN + c0 + 8 * gg;
                        float4 q0 = *(const float4*)up;
                        float4 q1 = *(const float4*)(up + 4);
                        v[0] = q0.x; v[1] = q0.y; v[2] = q0.z; v[3] = q0.w;
                        v[4] = q1.x; v[5] = q1.y; v[6] = q1.z; v[7] = q1.w;
                        if (BNIN) {
#pragma unroll
                            for (int j = 0; j < 8; j++) {
                                int chn = c0 + 8 * gg + j;
                                v[j] = fmaxf(fmaf(v[j], s_ss[2 * chn], s_ss[2 * chn + 1]), 0.f);
                            }
                        }
                    }
                } else {
#pragma unroll
                    for (int j = 0; j < 8; j++) v[j] = 0.f;
                }
                unsigned hp[4], lp[4];
#pragma unroll
                for (int j2 = 0; j2 < 4; j2++) {
                    bf16 h0b = __float2bfloat16(v[2 * j2]);
                    bf16 h1b = __float2bfloat16(v[2 * j2 + 1]);
                    hp[j2] = (unsigned)__bfloat16_as_ushort(h0b) |
                             ((unsigned)__bfloat16_as_ushort(h1b) << 16);
                    if (uselo) {
                        unsigned short l0 = __bfloat16_as_ushort(
                            __float2bfloat16(v[2 * j2] - b2f(h0b)));
                        unsigned short l1 = __bfloat16_as_ushort(
                            __float2bfloat16(v[2 * j2 + 1] - b2f(h1b)));
                        lp[j2] = (unsigned)l0 | ((unsigned)l1 << 16);
                    }
                }
                s_hi[gg * NPs + pixin] = make_int4(hp[0], hp[1], hp[2], hp[3]);
                if (uselo && !NOLO)
                    s_lo[gg * NPs + pixin] = make_int4(lp[0], lp[1], lp[2], lp[3]);
            }
        }
        __syncthreads();
        // ------- compute: 9 taps; ah held in regs across all 3 terms -------
#pragma unroll
        for (int tap = 0; tap < 9; tap++) {
            const int ky = tap / 3, kx = tap % 3;
            bfrag ah[4];
#pragma unroll
            for (int mf = 0; mf < 4; mf++) {
                int p = 64 * wpx + 16 * mf;
                int pix = ((p >> 6) + ky) * W2h + (p & 63) + kx + lx;
                ah[mf] = ((const bfrag*)s_hi)[gq * NPs + pix];
            }
            bfrag bh[NF];
#pragma unroll
            for (int nf = 0; nf < NF; nf++) {
                int fb = (tap * NCH + ch) * NCOG + coB * 4 + wco * NF + nf;
                bh[nf] = ((const bfrag*)(whi + (size_t)fb * 512))[lane];
            }
#pragma unroll
            for (int nf = 0; nf < NF; nf++)
#pragma unroll
                for (int mf = 0; mf < 4; mf++)
                    acc[mf][nf] = __builtin_amdgcn_mfma_f32_16x16x32_bf16(
                        ah[mf], bh[nf], acc[mf][nf], 0, 0, 0);
            if (!NOLO && uselo) {
                bfrag al[4];
#pragma unroll
                for (int mf = 0; mf < 4; mf++) {
                    int p = 64 * wpx + 16 * mf;
                    int pix = ((p >> 6) + ky) * W2h + (p & 63) + kx + lx;
                    al[mf] = ((const bfrag*)s_lo)[gq * NPs + pix];
                }
#pragma unroll
                for (int nf = 0; nf < NF; nf++)
#pragma unroll
                    for (int mf = 0; mf < 4; mf++)
                        acc[mf][nf] = __builtin_amdgcn_mfma_f32_16x16x32_bf16(
                            al[mf], bh[nf], acc[mf][nf], 0, 0, 0);
            }
            if (!isbf) {   // third term a_hi * w_lo (ah reused from regs)
                bfrag bl[NF];
#pragma unroll
                for (int nf = 0; nf < NF; nf++) {
                    int fb = (tap * NCH + ch) * NCOG + coB * 4 + wco * NF + nf;
                    bl[nf] = ((const bfrag*)(wlo + (size_t)fb * 512))[lane];
                }
#pragma unroll
                for (int nf = 0; nf < NF; nf++)
#pragma unroll
                    for (int mf = 0; mf < 4; mf++)
                        acc[mf][nf] = __builtin_amdgcn_mfma_f32_16x16x32_bf16(
                            ah[mf], bl[nf], acc[mf][nf], 0, 0, 0);
            }
        }
    }
    // ---------------- epilogue: NHWC f32 store (+ optional stats) ----------
    const float beta = EPI ? ldin(betap, 0, isbf) : 0.f;
    float sl[NF], s2l[NF];
#pragma unroll
    for (int nf = 0; nf < NF; nf++) { sl[nf] = 0.f; s2l[nf] = 0.f; }
#pragma unroll
    for (int nf = 0; nf < NF; nf++) {
        int co = coB * 64 + wco * STCO + nf * 16 + lx;
        float bi = ldin(bias, co, isbf);
#pragma unroll
        for (int mf = 0; mf < 4; mf++) {
#pragma unroll
            for (int r2 = 0; r2 < 4; r2++) {
                int p = 64 * wpx + 16 * mf + gq * 4 + r2;
                int grow = r0 + (p >> 6);
                int gcol = x0 + (p & 63);
                size_t oi = ((size_t)grow * W + gcol) * COUT + co;
                float vo = acc[mf][nf][r2] + bi;
                if (EPI) vo = dep[oi] + beta * vo;
                out[oi] = vo;
                if (STATS) {
                    sl[nf] += vo;
                    s2l[nf] = fmaf(vo, vo, s2l[nf]);
                }
            }
        }
    }
    if (STATS) {
        __syncthreads();   // all waves done with s_hi (s_st aliases it)
#pragma unroll
        for (int nf = 0; nf < NF; nf++) {
            float s = sl[nf], q = s2l[nf];
            s += __shfl_xor(s, 16, 64); s += __shfl_xor(s, 32, 64);
            q += __shfl_xor(q, 16, 64); q += __shfl_xor(q, 32, 64);
            if (gq == 0) {
                s_st[0][wv][nf * 16 + lx] = s;
                s_st[1][wv][nf * 16 + lx] = q;
            }
        }
        __syncthreads();
        if (tid < 128) {
            int which = tid >> 6, c = tid & 63;
            float v = 0.f;
            int wc = c / STCO, ci = c % STCO;
#pragma unroll
            for (int k = 0; k < ROWS; k++)
                v += s_st[which][wc + WCO * k][ci];
            atomicAdd(&sacc[which * statC + coB * 64 + c], v);
        }
    }
}

// ---------------------------------------------------------------------------
// pixel_shuffle(2) + BN + ReLU, NHWC: u1 [B*64*64][256] -> dep [B*128*128][64]
// ---------------------------------------------------------------------------
__global__ __launch_bounds__(256)
void shuffle_bn_nhwc_kernel(const float* __restrict__ u, const float* __restrict__ accum,
                            const void* __restrict__ g, const void* __restrict__ be,
                            float* __restrict__ dep, const int* __restrict__ flagp)
{
    int isbf = *flagp;
    int tid = threadIdx.x;
    int c = tid & 63, ps = tid >> 6;
    float sc[4], sh[4];
#pragma unroll
    for (int q = 0; q < 4; q++) {
        int chn = 4 * c + q;
        float S = accum[chn], S2 = accum[256 + chn];
        const float n = 65536.f;
        float m = S / n;
        float var = fmaxf(S2 / n - m * m, 0.f);
        sc[q] = ldin(g, chn, isbf) * rsqrtf(var + 1e-5f);
        sh[q] = ldin(be, chn, isbf) - m * sc[q];
    }
    for (int sp = blockIdx.x * 4 + ps; sp < 65536; sp += gridDim.x * 4) {
        float4 q4 = *(const float4*)(u + (size_t)sp * 256 + 4 * c);
        float vals[4] = {q4.x, q4.y, q4.z, q4.w};
        int b = sp >> 12, rem = sp & 4095, y2 = rem >> 6, x2 = rem & 63;
#pragma unroll
        for (int dy = 0; dy < 2; dy++)
#pragma unroll
            for (int dx = 0; dx < 2; dx++) {
                int q = 2 * dy + dx;
                float v = fmaxf(fmaf(vals[q], sc[q], sh[q]), 0.f);
                size_t op = (size_t)(b * 128 + 2 * y2 + dy) * 128 + (2 * x2 + dx);
                dep[op * 64 + c] = v;
            }
    }
}

// ---------------------------------------------------------------------------
// final BN+ReLU + NHWC->NCHW transpose.
// bf16 mode: write r3 f32 + d_out bf16.  f32 mode: d_out f32 only.
// ---------------------------------------------------------------------------
__global__ __launch_bounds__(256)
void bn_out_kernel(const float* __restrict__ u, const float* __restrict__ accum,
                   const void* __restrict__ g, const void* __restrict__ be,
                   float* __restrict__ r3, void* __restrict__ dout,
                   const int* __restrict__ flagp)
{
    int isbf = *flagp;
    int tid = threadIdx.x;
    int c = tid & 63, ps = tid >> 6;
    float S = accum[c], S2 = accum[64 + c];
    const float n = 262144.f;
    float m = S / n;
    float var = fmaxf(S2 / n - m * m, 0.f);
    float sc = ldin(g, c, isbf) * rsqrtf(var + 1e-5f);
    float sh = ldin(be, c, isbf) - m * sc;
    __shared__ float s[64][65];
    int pix0 = blockIdx.x * 64;
#pragma unroll
    for (int ii = 0; ii < 16; ii++) {
        int p = ps + 4 * ii;
        float v = u[(size_t)(pix0 + p) * 64 + c];
        s[p][c] = fmaxf(fmaf(v, sc, sh), 0.f);
    }
    __syncthreads();
    int x = c;
    int row = pix0 >> 7, col0 = pix0 & 127;
    int b = row >> 7, y = row & 127;
#pragma unroll
    for (int jj = 0; jj < 16; jj++) {
        int cc = ps + 4 * jj;
        float v = s[x][cc];
        size_t oi = (((size_t)(b * 64 + cc)) << 14) + (y << 7) + col0 + x;
        if (isbf) {
            r3[oi] = v;
            ((bf16*)dout)[oi] = __float2bfloat16(v);
        } else {
            ((float*)dout)[oi] = v;
        }
    }
}

// ---------------------------------------------------------------------------
// 7x7 conv 64->1, pad=3, NCHW f32 input, channel-split partials.
// Reads r3 ws (bf16 mode) or d_out's r region (f32 mode, identical bytes).
// ---------------------------------------------------------------------------
__global__ __launch_bounds__(256, 2)
void conv7x7_part_kernel(const float* __restrict__ r3ws, const void* __restrict__ dout,
                         const void* __restrict__ w,
                         float* __restrict__ outP, const int* __restrict__ flagp)
{
    __shared__ float s_in[4][70][22];
    __shared__ float s_w[16][49];
    const int isbf = *flagp;
    const float* r = isbf ? r3ws : (const float*)dout;
    int tid = threadIdx.x;
    int tx = tid & 15, ty = tid >> 4;
    int x0 = blockIdx.x * 16, y0 = blockIdx.y * 64;
    int b = blockIdx.z >> 2, g = blockIdx.z & 3;
    for (int i = tid; i < 16 * 49; i += 256) {
        int ci = i / 49, k = i - ci * 49;
        s_w[ci][k] = ldin(w, (g * 16 + ci) * 49 + k, isbf);
    }
    float acc[4] = {0.f, 0.f, 0.f, 0.f};

    for (int c0 = 0; c0 < 16; c0 += 4) {
        __syncthreads();
        for (int i = tid; i < 4 * 70 * 22; i += 256) {
            int ci = i / (70 * 22);
            int rem = i - ci * (70 * 22);
            int rr = rem / 22, cc = rem - rr * 22;
            int gy = y0 + rr - 3, gx = x0 + cc - 3;
            float v = 0.f;
            if ((unsigned)gy < 128u && (unsigned)gx < 128u)
                v = r[((b * 64 + g * 16 + c0 + ci) << 14) + (gy << 7) + gx];
            s_in[ci][rr][cc] = v;
        }
        __syncthreads();
        for (int ci = 0; ci < 4; ci++) {
            float wr[49];
#pragma unroll
            for (int k = 0; k < 49; k++) wr[k] = s_w[c0 + ci][k];
#pragma unroll
            for (int rr = 0; rr < 10; rr++) {
                float row[7];
#pragma unroll
                for (int c = 0; c < 7; c++) row[c] = s_in[ci][4 * ty + rr][tx + c];
#pragma unroll
                for (int oy = 0; oy < 4; oy++) {
                    int ky = rr - oy;
                    if (ky >= 0 && ky <= 6) {
#pragma unroll
                        for (int kx = 0; kx < 7; kx++)
                            acc[oy] = fmaf(row[kx], wr[ky * 7 + kx], acc[oy]);
                    }
                }
            }
        }
    }
#pragma unroll
    for (int oy = 0; oy < 4; oy++) {
        int y = y0 + 4 * ty + oy;
        outP[(g << 18) + (b << 14) + (y << 7) + x0 + tx] = acc[oy];
    }
}

// ---------------------------------------------------------------------------
// sum 4 channel-group partials + bias -> output_map at d_out + 16.7M
// ---------------------------------------------------------------------------
__global__ __launch_bounds__(256)
void finalize_out_kernel(const float* __restrict__ outP, const void* __restrict__ bias,
                         void* __restrict__ outv, const int* __restrict__ flagp)
{
    int isbf = *flagp;
    int i = blockIdx.x * 256 + threadIdx.x;   // 262144
    float bi = ldin(bias, 0, isbf);
    float v = (outP[i] + outP[i + 262144]) +
              (outP[i + 2 * 262144] + outP[i + 3 * 262144]) + bi;
    int oidx = 16777216 + i;
    if (isbf) ((bf16*)outv)[oidx] = __float2bfloat16(v);
    else      ((float*)outv)[oidx] = v;
}

// ---------------------------------------------------------------------------
// ws layout (134,221,828 B):
//   [0, 64MB)            W0  (u1 / t / u_d2 / r3-NCHW f32 [bf16 mode only])
//   [64MB, 128MB)        W1  (dep_x-NHWC-bf16 scratch / dep / u_d1 / u_d3 / outP)
//   [134217728, +3.5KB)  accum: a0[512] a1[128] a2[128] a3[128]
//   [134221824, +4B)     flag
// d_out head (dead until bn_out) holds scratch: split weights + imapF.
// ---------------------------------------------------------------------------
extern "C" void kernel_launch(void* const* d_in, const int* in_sizes, int n_in,
                              void* d_out, int out_size, void* d_ws, size_t ws_size,
                              hipStream_t stream)
{
    (void)in_sizes; (void)n_in; (void)out_size; (void)ws_size;

    const void* cur_x   = d_in[0];
    const void* dep_x   = d_in[1];
    const void* in_map  = d_in[2];
    const void* up_w    = d_in[3];
    const void* up_b    = d_in[4];
    const void* up_g    = d_in[5];
    const void* up_be   = d_in[6];
    const void* conv2_w = d_in[7];
    const void* conv2_b = d_in[8];
    const void* beta    = d_in[9];
    const void* d1_w = d_in[10];
    const void* d1_b = d_in[11];
    const void* d1_g = d_in[12];
    const void* d1_be = d_in[13];
    const void* d2_w = d_in[14];
    const void* d2_b = d_in[15];
    const void* d2_g = d_in[16];
    const void* d2_be = d_in[17];
    const void* d3_w = d_in[18];
    const void* d3_b = d_in[19];
    const void* d3_g = d_in[20];
    const void* d3_be = d_in[21];
    const void* out_w = d_in[22];
    const void* out_b = d_in[23];

    char* ws = (char*)d_ws;
    float* W0    = (float*)ws;
    float* W1    = (float*)(ws + 67108864);
    float* accum = (float*)(ws + 134217728);
    int*   flag  = (int*)(ws + 134221824);
    float* a0 = accum;
    float* a1 = accum + 512;
    float* a2 = accum + 640;
    float* a3 = accum + 768;

    char* sc = (char*)d_out;   // dead scratch until bn_out
    unsigned short* wbase = (unsigned short*)sc;
    unsigned short* whi1  = wbase;                        // 294912 elems
    unsigned short* wlo1  = whi1 + 294912;
    unsigned short* whi2  = wlo1 + 294912;                // offset 589824
    unsigned short* wlo2  = whi2 + 36864;
    unsigned short* whiD1 = wlo2 + 36864;
    unsigned short* wloD1 = whiD1 + 36864;
    unsigned short* whiD2 = wloD1 + 36864;
    unsigned short* wloD2 = whiD2 + 36864;
    unsigned short* whiD3 = wloD2 + 36864;
    unsigned short* wloD3 = whiD3 + 36864;
    float* imapF = (float*)(sc + 1769472);                // 1MB

    // 0. fused prep: detect + accum zero + weight splits + dep NHWC + imap
    prep_all_kernel<<<4800, 256, 0, stream>>>((const unsigned*)cur_x,
        up_w, conv2_w, d1_w, d2_w, d3_w, dep_x, in_map,
        wbase, (unsigned short*)W1, imapF, accum, flag);

    // 1. u1 = conv3x3(dep_x-NHWC; up) -> W0 NHWC [65536][256] ; stats -> a0
    //    512-thr blocks (ROWS=4, WCO=2). bf16 variant: ~25.6K LDS -> 4 blk/CU;
    //    f32 variant: ~51K LDS -> 3 blk/CU (24 waves). Wrong dtype early-exits.
    conv3_mfma<128, 256, 64, 64, 4, 2, 2, false, false, false, true, 8, 1, true>
        <<<dim3(256, 4), 512, 0, stream>>>((const void*)W1, whi1, wlo1, up_b,
            nullptr, nullptr, nullptr, nullptr, nullptr, nullptr, W0, flag, a0, 256);
    conv3_mfma<128, 256, 64, 64, 4, 2, 2, false, false, false, true, 6, 0, true>
        <<<dim3(256, 4), 512, 0, stream>>>((const void*)W1, whi1, wlo1, up_b,
            nullptr, nullptr, nullptr, nullptr, nullptr, nullptr, W0, flag, a0, 256);
    // 2. dep = shuffle(relu(bn(u1))) -> W1 NHWC [262144][64]
    shuffle_bn_nhwc_kernel<<<2048, 256, 0, stream>>>(W0, a0, up_g, up_be, W1, flag);
    // 3. t = dep + beta*conv3x3(cur_x * inc) -> W0 (inc computed inline)
    conv3_mfma<64, 64, 128, 128, 4, 2, 1, true, true, false, false, 6, -1, true>
        <<<dim3(1024, 1), 512, 0, stream>>>(cur_x, whi2, wlo2, conv2_b,
            imapF, W1, beta, nullptr, nullptr, nullptr, W0, flag, nullptr, 0);
    // 4. u_d1 = conv(t; d1) -> W1 ; stats -> a1
    conv3_mfma<64, 64, 128, 128, 4, 2, 0, false, false, false, true, 6, -1, true>
        <<<dim3(1024, 1), 512, 0, stream>>>(W0, whiD1, wloD1, d1_b,
            nullptr, nullptr, nullptr, nullptr, nullptr, nullptr, W1, flag, a1, 64);
    // 5. u_d2 = conv(relu(bn1(u_d1)); d2) -> W0 ; stats -> a2
    conv3_mfma<64, 64, 128, 128, 4, 2, 0, false, false, true, true, 6, -1, true>
        <<<dim3(1024, 1), 512, 0, stream>>>(W1, whiD2, wloD2, d2_b,
            nullptr, nullptr, nullptr, a1, d1_g, d1_be, W0, flag, a2, 64);
    // 6. u_d3 = conv(relu(bn2(u_d2)); d3) -> W1 ; stats -> a3
    conv3_mfma<64, 64, 128, 128, 4, 2, 0, false, false, true, true, 6, -1, true>
        <<<dim3(1024, 1), 512, 0, stream>>>(W0, whiD3, wloD3, d3_b,
            nullptr, nullptr, nullptr, a2, d2_g, d2_be, W1, flag, a3, 64);
    // 7. r3 = relu(bn3(u_d3)) -> d_out (+ W0 f32 copy only in bf16 mode)
    bn_out_kernel<<<4096, 256, 0, stream>>>(W1, a3, d3_g, d3_be, W0, d_out, flag);
    // 8. 7x7 conv partials (channel-split x4) -> W1[0:4MB]
    conv7x7_part_kernel<<<dim3(8, 2, 64), 256, 0, stream>>>(W0, d_out, out_w, W1, flag);
    // 9. output_map = sum partials + bias -> d_out + 16.7M
    finalize_out_kernel<<<1024, 256, 0, stream>>>(W1, out_b, d_out, flag);
}

// Round 9
// 720.821 us; speedup vs baseline: 1.3666x; 1.3666x over previous
//
#include <hip/hip_runtime.h>
#include <hip/hip_bf16.h>

using bf16 = __hip_bfloat16;
typedef __attribute__((ext_vector_type(8))) short bfrag;   // 8 x bf16 (4 VGPR)
typedef __attribute__((ext_vector_type(4))) float ffrag;   // 4 x f32 acc

__device__ __forceinline__ float b2f(bf16 v) { return __bfloat162float(v); }
__device__ __forceinline__ float ldin(const void* p, int i, int isbf) {
    return isbf ? b2f(((const bf16*)p)[i]) : ((const float*)p)[i];
}
// exact-ish two-term bf16 split: v ~= hi + lo, |err| <= 2^-17 |v|
__device__ __forceinline__ void split2(float v, unsigned short& h, unsigned short& l) {
    bf16 hb = __float2bfloat16(v);
    h = __bfloat16_as_ushort(hb);
    l = __bfloat16_as_ushort(__float2bfloat16(v - __bfloat162float(hb)));
}

// ---------------------------------------------------------------------------
// fused prep: every block re-votes dtype locally from cur_x[0:256].
//   bid <  1728 : 3x3 weight pre-split (5 tensors) -> wbase
//   1728..3775  : dep_x NCHW -> NHWC bf16 hi(/lo) planes -> depout
//   3776..4799  : imap = sigmoid(up2_bilinear(in_map)) -> imapF
// block 0 additionally publishes flag + zeroes accum.
// ---------------------------------------------------------------------------
__global__ __launch_bounds__(256)
void prep_all_kernel(const unsigned* __restrict__ cur_x,
                     const void* __restrict__ up_w, const void* __restrict__ c2_w,
                     const void* __restrict__ d1_w, const void* __restrict__ d2_w,
                     const void* __restrict__ d3_w,
                     const void* __restrict__ dep_x, const void* __restrict__ in_map,
                     unsigned short* __restrict__ wbase,
                     unsigned short* __restrict__ depout,
                     float* __restrict__ imapF,
                     float* __restrict__ accum, int* __restrict__ flagout)
{
    __shared__ unsigned short s_h[64][65];
    __shared__ unsigned short s_l[64][65];
    __shared__ int s_flag;
    const int tid = threadIdx.x;
    if (tid < 64) {
        int cnt = 0;
        for (int i = tid; i < 256; i += 64) {
            unsigned e = (cur_x[i] >> 7) & 0xFFu;
            cnt += (e >= 110u && e <= 135u) ? 1 : 0;
        }
#pragma unroll
        for (int off = 32; off > 0; off >>= 1) cnt += __shfl_down(cnt, off, 64);
        if (tid == 0) s_flag = (cnt >= 128) ? 1 : 0;
    }
    __syncthreads();
    const int isbf = s_flag;
    const int bid = blockIdx.x;
    if (bid == 0) {
        if (tid == 0) *flagout = isbf;
        for (int i = tid; i < 896; i += 256) accum[i] = 0.f;
    }
    if (bid < 1728) {
        int o = bid * 256 + tid;
        if (o >= 442368) return;
        const void* w;
        int CIN, NCH, NCOG, lo;
        size_t hoff, losz;
        if (o < 294912) {
            w = up_w; CIN = 128; NCH = 4; NCOG = 16; hoff = 0; lo = o; losz = 294912;
        } else {
            int t = (o - 294912) / 36864;
            lo = (o - 294912) - t * 36864;
            CIN = 64; NCH = 2; NCOG = 4;
            hoff = 589824 + (size_t)t * 73728;
            losz = 36864;
            w = (t == 0) ? c2_w : (t == 1) ? d1_w : (t == 2) ? d2_w : d3_w;
        }
        int j = lo & 7;
        int l = (lo >> 3) & 63;
        int fb = lo >> 9;
        int cg = fb % NCOG;
        int t2 = fb / NCOG;
        int ch = t2 % NCH;
        int tap = t2 / NCH;
        int co = cg * 16 + (l & 15);
        int ci = ch * 32 + (l >> 4) * 8 + j;
        float v = ldin(w, (co * CIN + ci) * 9 + tap, isbf);
        unsigned short h, l2;
        split2(v, h, l2);
        wbase[hoff + lo] = h;
        wbase[hoff + losz + lo] = l2;
    } else if (bid < 3776) {
        int lid = bid - 1728;
        int pb = lid & 63, cb = (lid >> 6) & 1, b = lid >> 7;
        for (int i = tid; i < 4096; i += 256) {
            int ci = i >> 6, pi = i & 63;
            float v = ldin(dep_x, ((b * 128 + cb * 64 + ci) << 12) + (pb << 6) + pi, isbf);
            unsigned short h, l;
            split2(v, h, l);
            s_h[ci][pi] = h;
            if (!isbf) s_l[ci][pi] = l;
        }
        __syncthreads();
        for (int i = tid; i < 4096; i += 256) {
            int ci = i & 63, pi = i >> 6;
            size_t o = ((size_t)(b * 4096 + pb * 64 + pi) << 7) + cb * 64 + ci;
            depout[o] = s_h[ci][pi];
            if (!isbf) depout[8388608 + o] = s_l[ci][pi];
        }
    } else {
        int idx = (bid - 3776) * 256 + tid;   // 262144 total
        int x = idx & 127, y = (idx >> 7) & 127, b = idx >> 14;
        const float s = (float)(63.0 / 127.0);
        float yy = y * s, xx = x * s;
        int y0 = (int)yy, x0 = (int)xx;
        float wy = yy - y0, wx = xx - x0;
        int y1 = min(y0 + 1, 63), x1 = min(x0 + 1, 63);
        int base = b << 12;
        float v00 = ldin(in_map, base + (y0 << 6) + x0, isbf);
        float v01 = ldin(in_map, base + (y0 << 6) + x1, isbf);
        float v10 = ldin(in_map, base + (y1 << 6) + x0, isbf);
        float v11 = ldin(in_map, base + (y1 << 6) + x1, isbf);
        float r0 = v00 * (1.f - wy) + v10 * wy;
        float r1 = v01 * (1.f - wy) + v11 * wy;
        float v = r0 * (1.f - wx) + r1 * wx;
        imapF[idx] = 1.f / (1.f + expf(-v));
    }
}

// ---------------------------------------------------------------------------
// MFMA implicit-GEMM 3x3 conv, pad=1, NHWC f32 output u = conv + bias.
// Block: ROWS x 64 px tile, 64 couts; ROWS*WCO waves = ROWS(px) x WCO(co);
// block dim = 64*ROWS*WCO threads.
// MINW is min waves per SIMD (EU): gfx950 occupancy steps at VGPR 64/128/256
// -> 8/4/2 waves per SIMD. MINW must be a step value; MINW=6 (R8) forced the
// allocator under the 64-VGPR cliff -> acc spill -> 200MB scratch traffic.
// Use MINW=4 (VGPR cap 128; kernel needs ~60-90; 2 blocks/CU x 8 waves).
// MODE: 0 = NHWC f32 intermediate; 1 = NCHW flag-dtype external;
//       2 = NHWC bf16 pre-split hi/lo planes.
// DTMODE: -1 runtime; 0/1 compile-time + runtime guard (early exit).
// SWZ: XCD-aware blockIdx.x swizzle (gridDim.x % 8 == 0 required).
// ---------------------------------------------------------------------------
template<int CIN, int COUT, int H, int W, int ROWS, int WCO, int MODE,
         bool SMAP, bool EPI, bool BNIN, bool STATS, int MINW,
         int DTMODE = -1, bool SWZ = false>
__global__ __launch_bounds__(64 * ROWS * WCO, MINW)
void conv3_mfma(const void* __restrict__ in,
                const unsigned short* __restrict__ whi,
                const unsigned short* __restrict__ wlo,
                const void* __restrict__ bias,
                const float* __restrict__ imapF,
                const float* __restrict__ dep,
                const void* __restrict__ betap,
                const float* __restrict__ accum,
                const void* __restrict__ bng, const void* __restrict__ bnbe,
                float* __restrict__ out, const int* __restrict__ flagp,
                float* __restrict__ sacc, int statC)
{
    constexpr int NWAVES = ROWS * WCO;
    constexpr int NTHR = 64 * NWAVES;
    constexpr int NCH  = CIN / 32;
    constexpr int NCOG = COUT / 16;
    constexpr int NCT  = W / 64;
    constexpr int W2h  = 66;
    constexpr int NP   = (ROWS + 2) * W2h;
    constexpr int NPs  = NP + 1;
    constexpr int NE   = 4 * NP;
    constexpr int NIT  = (NE + NTHR - 1) / NTHR;
    constexpr int NF   = (64 / WCO) / 16;
    constexpr int STCO = 64 / WCO;
    constexpr size_t PLANE = (size_t)16 * H * W * CIN;
    constexpr bool NOLO = (DTMODE == 1) && (MODE == 2) && !SMAP;

    if (DTMODE >= 0 && *flagp != DTMODE) return;
    const int isbf = (DTMODE >= 0) ? DTMODE : *flagp;

    __shared__ int4 s_hi[4 * NPs];
    __shared__ int4 s_lo[NOLO ? 1 : 4 * NPs];
    __shared__ float s_ss[BNIN ? 128 : 1];
    __shared__ float s_sm[SMAP ? NP : 1];
    float (*s_st)[NWAVES][STCO] = (float (*)[NWAVES][STCO])s_hi;  // post-loop alias

    const bool uselo = !(isbf && (MODE == 2 || (MODE == 1 && !SMAP)));
    const int tid  = threadIdx.x;
    int bidx = blockIdx.x;
    if (SWZ) bidx = ((bidx & 7) * (gridDim.x >> 3)) + (bidx >> 3);
    const int r0   = (bidx / NCT) * ROWS;     // global row in [0, 16*H)
    const int x0   = (bidx % NCT) * 64;
    const int bimg = r0 / H;
    const int y0im = bimg * H;
    const int coB  = blockIdx.y;

    if (BNIN) {
        if (tid < CIN) {
            const float n = (float)(16 * H * W);
            float S = accum[tid], S2 = accum[CIN + tid];
            float m = S / n;
            float var = fmaxf(S2 / n - m * m, 0.f);
            float scv = ldin(bng, tid, isbf) * rsqrtf(var + 1e-5f);
            s_ss[2 * tid]     = scv;
            s_ss[2 * tid + 1] = ldin(bnbe, tid, isbf) - m * scv;
        }
    }
    if (SMAP) {
        const float* ip = imapF + ((size_t)bimg << 14);   // H=W=128 only
        for (int i = tid; i < NP; i += NTHR) {
            int rr = i / W2h, cc = i - rr * W2h;
            int gy = r0 - 1 + rr, gx = x0 - 1 + cc;
            float sm = 0.f;
            if (gy >= y0im && gy < y0im + H && (unsigned)gx < (unsigned)W) {
                int y = gy - y0im;
                float ctr = ip[(y << 7) + gx];
                float mx = ctr;
#pragma unroll
                for (int dy = -1; dy <= 1; dy++) {
                    int yy = y + dy;
                    if ((unsigned)yy < 128u) {
#pragma unroll
                        for (int dx = -1; dx <= 1; dx++) {
                            int xx = gx + dx;
                            if ((unsigned)xx < 128u) mx = fmaxf(mx, ip[(yy << 7) + xx]);
                        }
                    }
                }
                sm = mx - ctr;
            }
            s_sm[i] = sm;
        }
    }

    const int lane = tid & 63;
    const int wv = tid >> 6;
    const int wpx = wv / WCO, wco = wv % WCO;
    const int lx = lane & 15;
    const int gq = lane >> 4;

    ffrag acc[4][NF];
#pragma unroll
    for (int mf = 0; mf < 4; mf++)
#pragma unroll
        for (int nf = 0; nf < NF; nf++) acc[mf][nf] = ffrag{0.f, 0.f, 0.f, 0.f};

    for (int ch = 0; ch < NCH; ch++) {
        const int c0 = ch * 32;
        __syncthreads();
        // ---------------- stage halo tile (32 channels) ----------------
#pragma unroll
        for (int it = 0; it < NIT; it++) {
            int e = tid + it * NTHR;
            if (e >= NE) break;
            int gg, pixin;
            if (MODE == 1) { gg = e / NP; pixin = e - gg * NP; }
            else           { gg = e & 3;  pixin = e >> 2; }
            int rr = pixin / W2h;
            int cc2 = pixin - rr * W2h;
            int gy = r0 - 1 + rr;
            int gx = x0 - 1 + cc2;
            bool ok = (gy >= y0im) && (gy < y0im + H) && ((unsigned)gx < (unsigned)W);
            if (MODE == 2) {
                int4 hv = make_int4(0, 0, 0, 0), lv = make_int4(0, 0, 0, 0);
                if (ok) {
                    size_t eb = (size_t)(gy * W + gx) * CIN + c0 + 8 * gg;
                    hv = *(const int4*)((const unsigned short*)in + eb);
                    if (!isbf) lv = *(const int4*)((const unsigned short*)in + PLANE + eb);
                }
                s_hi[gg * NPs + pixin] = hv;
                if (!isbf && !NOLO) s_lo[gg * NPs + pixin] = lv;
            } else {
                float v[8];
                if (ok) {
                    if (MODE == 1) {
                        int y = gy - y0im;
                        float sm = SMAP ? s_sm[pixin] : 1.f;
#pragma unroll
                        for (int j = 0; j < 8; j++) {
                            int gi = ((bimg * CIN + c0 + 8 * gg + j) * H + y) * W + gx;
                            v[j] = ldin(in, gi, isbf) * sm;
                        }
                    } else {
                        const float* up = (const float*)in +
                            ((size_t)gy * W + gx) * CIN + c0 + 8 * gg;
                        float4 q0 = *(const float4*)up;
                        float4 q1 = *(const float4*)(up + 4);
                        v[0] = q0.x; v[1] = q0.y; v[2] = q0.z; v[3] = q0.w;
                        v[4] = q1.x; v[5] = q1.y; v[6] = q1.z; v[7] = q1.w;
                        if (BNIN) {
#pragma unroll
                            for (int j = 0; j < 8; j++) {
                                int chn = c0 + 8 * gg + j;
                                v[j] = fmaxf(fmaf(v[j], s_ss[2 * chn], s_ss[2 * chn + 1]), 0.f);
                            }
                        }
                    }
                } else {
#pragma unroll
                    for (int j = 0; j < 8; j++) v[j] = 0.f;
                }
                unsigned hp[4], lp[4];
#pragma unroll
                for (int j2 = 0; j2 < 4; j2++) {
                    bf16 h0b = __float2bfloat16(v[2 * j2]);
                    bf16 h1b = __float2bfloat16(v[2 * j2 + 1]);
                    hp[j2] = (unsigned)__bfloat16_as_ushort(h0b) |
                             ((unsigned)__bfloat16_as_ushort(h1b) << 16);
                    if (uselo) {
                        unsigned short l0 = __bfloat16_as_ushort(
                            __float2bfloat16(v[2 * j2] - b2f(h0b)));
                        unsigned short l1 = __bfloat16_as_ushort(
                            __float2bfloat16(v[2 * j2 + 1] - b2f(h1b)));
                        lp[j2] = (unsigned)l0 | ((unsigned)l1 << 16);
                    }
                }
                s_hi[gg * NPs + pixin] = make_int4(hp[0], hp[1], hp[2], hp[3]);
                if (uselo && !NOLO)
                    s_lo[gg * NPs + pixin] = make_int4(lp[0], lp[1], lp[2], lp[3]);
            }
        }
        __syncthreads();
        // ------- compute: 9 taps; ah held in regs across all 3 terms -------
#pragma unroll
        for (int tap = 0; tap < 9; tap++) {
            const int ky = tap / 3, kx = tap % 3;
            bfrag ah[4];
#pragma unroll
            for (int mf = 0; mf < 4; mf++) {
                int p = 64 * wpx + 16 * mf;
                int pix = ((p >> 6) + ky) * W2h + (p & 63) + kx + lx;
                ah[mf] = ((const bfrag*)s_hi)[gq * NPs + pix];
            }
            bfrag bh[NF];
#pragma unroll
            for (int nf = 0; nf < NF; nf++) {
                int fb = (tap * NCH + ch) * NCOG + coB * 4 + wco * NF + nf;
                bh[nf] = ((const bfrag*)(whi + (size_t)fb * 512))[lane];
            }
#pragma unroll
            for (int nf = 0; nf < NF; nf++)
#pragma unroll
                for (int mf = 0; mf < 4; mf++)
                    acc[mf][nf] = __builtin_amdgcn_mfma_f32_16x16x32_bf16(
                        ah[mf], bh[nf], acc[mf][nf], 0, 0, 0);
            if (!NOLO && uselo) {
                bfrag al[4];
#pragma unroll
                for (int mf = 0; mf < 4; mf++) {
                    int p = 64 * wpx + 16 * mf;
                    int pix = ((p >> 6) + ky) * W2h + (p & 63) + kx + lx;
                    al[mf] = ((const bfrag*)s_lo)[gq * NPs + pix];
                }
#pragma unroll
                for (int nf = 0; nf < NF; nf++)
#pragma unroll
                    for (int mf = 0; mf < 4; mf++)
                        acc[mf][nf] = __builtin_amdgcn_mfma_f32_16x16x32_bf16(
                            al[mf], bh[nf], acc[mf][nf], 0, 0, 0);
            }
            if (!isbf) {   // third term a_hi * w_lo (ah reused from regs)
                bfrag bl[NF];
#pragma unroll
                for (int nf = 0; nf < NF; nf++) {
                    int fb = (tap * NCH + ch) * NCOG + coB * 4 + wco * NF + nf;
                    bl[nf] = ((const bfrag*)(wlo + (size_t)fb * 512))[lane];
                }
#pragma unroll
                for (int nf = 0; nf < NF; nf++)
#pragma unroll
                    for (int mf = 0; mf < 4; mf++)
                        acc[mf][nf] = __builtin_amdgcn_mfma_f32_16x16x32_bf16(
                            ah[mf], bl[nf], acc[mf][nf], 0, 0, 0);
            }
        }
    }
    // ---------------- epilogue: NHWC f32 store (+ optional stats) ----------
    const float beta = EPI ? ldin(betap, 0, isbf) : 0.f;
    float sl[NF], s2l[NF];
#pragma unroll
    for (int nf = 0; nf < NF; nf++) { sl[nf] = 0.f; s2l[nf] = 0.f; }
#pragma unroll
    for (int nf = 0; nf < NF; nf++) {
        int co = coB * 64 + wco * STCO + nf * 16 + lx;
        float bi = ldin(bias, co, isbf);
#pragma unroll
        for (int mf = 0; mf < 4; mf++) {
#pragma unroll
            for (int r2 = 0; r2 < 4; r2++) {
                int p = 64 * wpx + 16 * mf + gq * 4 + r2;
                int grow = r0 + (p >> 6);
                int gcol = x0 + (p & 63);
                size_t oi = ((size_t)grow * W + gcol) * COUT + co;
                float vo = acc[mf][nf][r2] + bi;
                if (EPI) vo = dep[oi] + beta * vo;
                out[oi] = vo;
                if (STATS) {
                    sl[nf] += vo;
                    s2l[nf] = fmaf(vo, vo, s2l[nf]);
                }
            }
        }
    }
    if (STATS) {
        __syncthreads();   // all waves done with s_hi (s_st aliases it)
#pragma unroll
        for (int nf = 0; nf < NF; nf++) {
            float s = sl[nf], q = s2l[nf];
            s += __shfl_xor(s, 16, 64); s += __shfl_xor(s, 32, 64);
            q += __shfl_xor(q, 16, 64); q += __shfl_xor(q, 32, 64);
            if (gq == 0) {
                s_st[0][wv][nf * 16 + lx] = s;
                s_st[1][wv][nf * 16 + lx] = q;
            }
        }
        __syncthreads();
        if (tid < 128) {
            int which = tid >> 6, c = tid & 63;
            float v = 0.f;
            int wc = c / STCO, ci = c % STCO;
#pragma unroll
            for (int k = 0; k < ROWS; k++)
                v += s_st[which][wc + WCO * k][ci];
            atomicAdd(&sacc[which * statC + coB * 64 + c], v);
        }
    }
}

// ---------------------------------------------------------------------------
// pixel_shuffle(2) + BN + ReLU, NHWC: u1 [B*64*64][256] -> dep [B*128*128][64]
// ---------------------------------------------------------------------------
__global__ __launch_bounds__(256)
void shuffle_bn_nhwc_kernel(const float* __restrict__ u, const float* __restrict__ accum,
                            const void* __restrict__ g, const void* __restrict__ be,
                            float* __restrict__ dep, const int* __restrict__ flagp)
{
    int isbf = *flagp;
    int tid = threadIdx.x;
    int c = tid & 63, ps = tid >> 6;
    float sc[4], sh[4];
#pragma unroll
    for (int q = 0; q < 4; q++) {
        int chn = 4 * c + q;
        float S = accum[chn], S2 = accum[256 + chn];
        const float n = 65536.f;
        float m = S / n;
        float var = fmaxf(S2 / n - m * m, 0.f);
        sc[q] = ldin(g, chn, isbf) * rsqrtf(var + 1e-5f);
        sh[q] = ldin(be, chn, isbf) - m * sc[q];
    }
    for (int sp = blockIdx.x * 4 + ps; sp < 65536; sp += gridDim.x * 4) {
        float4 q4 = *(const float4*)(u + (size_t)sp * 256 + 4 * c);
        float vals[4] = {q4.x, q4.y, q4.z, q4.w};
        int b = sp >> 12, rem = sp & 4095, y2 = rem >> 6, x2 = rem & 63;
#pragma unroll
        for (int dy = 0; dy < 2; dy++)
#pragma unroll
            for (int dx = 0; dx < 2; dx++) {
                int q = 2 * dy + dx;
                float v = fmaxf(fmaf(vals[q], sc[q], sh[q]), 0.f);
                size_t op = (size_t)(b * 128 + 2 * y2 + dy) * 128 + (2 * x2 + dx);
                dep[op * 64 + c] = v;
            }
    }
}

// ---------------------------------------------------------------------------
// final BN+ReLU + NHWC->NCHW transpose.
// bf16 mode: write r3 f32 + d_out bf16.  f32 mode: d_out f32 only.
// ---------------------------------------------------------------------------
__global__ __launch_bounds__(256)
void bn_out_kernel(const float* __restrict__ u, const float* __restrict__ accum,
                   const void* __restrict__ g, const void* __restrict__ be,
                   float* __restrict__ r3, void* __restrict__ dout,
                   const int* __restrict__ flagp)
{
    int isbf = *flagp;
    int tid = threadIdx.x;
    int c = tid & 63, ps = tid >> 6;
    float S = accum[c], S2 = accum[64 + c];
    const float n = 262144.f;
    float m = S / n;
    float var = fmaxf(S2 / n - m * m, 0.f);
    float sc = ldin(g, c, isbf) * rsqrtf(var + 1e-5f);
    float sh = ldin(be, c, isbf) - m * sc;
    __shared__ float s[64][65];
    int pix0 = blockIdx.x * 64;
#pragma unroll
    for (int ii = 0; ii < 16; ii++) {
        int p = ps + 4 * ii;
        float v = u[(size_t)(pix0 + p) * 64 + c];
        s[p][c] = fmaxf(fmaf(v, sc, sh), 0.f);
    }
    __syncthreads();
    int x = c;
    int row = pix0 >> 7, col0 = pix0 & 127;
    int b = row >> 7, y = row & 127;
#pragma unroll
    for (int jj = 0; jj < 16; jj++) {
        int cc = ps + 4 * jj;
        float v = s[x][cc];
        size_t oi = (((size_t)(b * 64 + cc)) << 14) + (y << 7) + col0 + x;
        if (isbf) {
            r3[oi] = v;
            ((bf16*)dout)[oi] = __float2bfloat16(v);
        } else {
            ((float*)dout)[oi] = v;
        }
    }
}

// ---------------------------------------------------------------------------
// 7x7 conv 64->1, pad=3, NCHW f32 input, channel-split partials.
// Reads r3 ws (bf16 mode) or d_out's r region (f32 mode, identical bytes).
// ---------------------------------------------------------------------------
__global__ __launch_bounds__(256, 2)
void conv7x7_part_kernel(const float* __restrict__ r3ws, const void* __restrict__ dout,
                         const void* __restrict__ w,
                         float* __restrict__ outP, const int* __restrict__ flagp)
{
    __shared__ float s_in[4][70][22];
    __shared__ float s_w[16][49];
    const int isbf = *flagp;
    const float* r = isbf ? r3ws : (const float*)dout;
    int tid = threadIdx.x;
    int tx = tid & 15, ty = tid >> 4;
    int x0 = blockIdx.x * 16, y0 = blockIdx.y * 64;
    int b = blockIdx.z >> 2, g = blockIdx.z & 3;
    for (int i = tid; i < 16 * 49; i += 256) {
        int ci = i / 49, k = i - ci * 49;
        s_w[ci][k] = ldin(w, (g * 16 + ci) * 49 + k, isbf);
    }
    float acc[4] = {0.f, 0.f, 0.f, 0.f};

    for (int c0 = 0; c0 < 16; c0 += 4) {
        __syncthreads();
        for (int i = tid; i < 4 * 70 * 22; i += 256) {
            int ci = i / (70 * 22);
            int rem = i - ci * (70 * 22);
            int rr = rem / 22, cc = rem - rr * 22;
            int gy = y0 + rr - 3, gx = x0 + cc - 3;
            float v = 0.f;
            if ((unsigned)gy < 128u && (unsigned)gx < 128u)
                v = r[((b * 64 + g * 16 + c0 + ci) << 14) + (gy << 7) + gx];
            s_in[ci][rr][cc] = v;
        }
        __syncthreads();
        for (int ci = 0; ci < 4; ci++) {
            float wr[49];
#pragma unroll
            for (int k = 0; k < 49; k++) wr[k] = s_w[c0 + ci][k];
#pragma unroll
            for (int rr = 0; rr < 10; rr++) {
                float row[7];
#pragma unroll
                for (int c = 0; c < 7; c++) row[c] = s_in[ci][4 * ty + rr][tx + c];
#pragma unroll
                for (int oy = 0; oy < 4; oy++) {
                    int ky = rr - oy;
                    if (ky >= 0 && ky <= 6) {
#pragma unroll
                        for (int kx = 0; kx < 7; kx++)
                            acc[oy] = fmaf(row[kx], wr[ky * 7 + kx], acc[oy]);
                    }
                }
            }
        }
    }
#pragma unroll
    for (int oy = 0; oy < 4; oy++) {
        int y = y0 + 4 * ty + oy;
        outP[(g << 18) + (b << 14) + (y << 7) + x0 + tx] = acc[oy];
    }
}

// ---------------------------------------------------------------------------
// sum 4 channel-group partials + bias -> output_map at d_out + 16.7M
// ---------------------------------------------------------------------------
__global__ __launch_bounds__(256)
void finalize_out_kernel(const float* __restrict__ outP, const void* __restrict__ bias,
                         void* __restrict__ outv, const int* __restrict__ flagp)
{
    int isbf = *flagp;
    int i = blockIdx.x * 256 + threadIdx.x;   // 262144
    float bi = ldin(bias, 0, isbf);
    float v = (outP[i] + outP[i + 262144]) +
              (outP[i + 2 * 262144] + outP[i + 3 * 262144]) + bi;
    int oidx = 16777216 + i;
    if (isbf) ((bf16*)outv)[oidx] = __float2bfloat16(v);
    else      ((float*)outv)[oidx] = v;
}

// ---------------------------------------------------------------------------
// ws layout (134,221,828 B):
//   [0, 64MB)            W0  (u1 / t / u_d2 / r3-NCHW f32 [bf16 mode only])
//   [64MB, 128MB)        W1  (dep_x-NHWC-bf16 scratch / dep / u_d1 / u_d3 / outP)
//   [134217728, +3.5KB)  accum: a0[512] a1[128] a2[128] a3[128]
//   [134221824, +4B)     flag
// d_out head (dead until bn_out) holds scratch: split weights + imapF.
// ---------------------------------------------------------------------------
extern "C" void kernel_launch(void* const* d_in, const int* in_sizes, int n_in,
                              void* d_out, int out_size, void* d_ws, size_t ws_size,
                              hipStream_t stream)
{
    (void)in_sizes; (void)n_in; (void)out_size; (void)ws_size;

    const void* cur_x   = d_in[0];
    const void* dep_x   = d_in[1];
    const void* in_map  = d_in[2];
    const void* up_w    = d_in[3];
    const void* up_b    = d_in[4];
    const void* up_g    = d_in[5];
    const void* up_be   = d_in[6];
    const void* conv2_w = d_in[7];
    const void* conv2_b = d_in[8];
    const void* beta    = d_in[9];
    const void* d1_w = d_in[10];
    const void* d1_b = d_in[11];
    const void* d1_g = d_in[12];
    const void* d1_be = d_in[13];
    const void* d2_w = d_in[14];
    const void* d2_b = d_in[15];
    const void* d2_g = d_in[16];
    const void* d2_be = d_in[17];
    const void* d3_w = d_in[18];
    const void* d3_b = d_in[19];
    const void* d3_g = d_in[20];
    const void* d3_be = d_in[21];
    const void* out_w = d_in[22];
    const void* out_b = d_in[23];

    char* ws = (char*)d_ws;
    float* W0    = (float*)ws;
    float* W1    = (float*)(ws + 67108864);
    float* accum = (float*)(ws + 134217728);
    int*   flag  = (int*)(ws + 134221824);
    float* a0 = accum;
    float* a1 = accum + 512;
    float* a2 = accum + 640;
    float* a3 = accum + 768;

    char* sc = (char*)d_out;   // dead scratch until bn_out
    unsigned short* wbase = (unsigned short*)sc;
    unsigned short* whi1  = wbase;                        // 294912 elems
    unsigned short* wlo1  = whi1 + 294912;
    unsigned short* whi2  = wlo1 + 294912;                // offset 589824
    unsigned short* wlo2  = whi2 + 36864;
    unsigned short* whiD1 = wlo2 + 36864;
    unsigned short* wloD1 = whiD1 + 36864;
    unsigned short* whiD2 = wloD1 + 36864;
    unsigned short* wloD2 = whiD2 + 36864;
    unsigned short* whiD3 = wloD2 + 36864;
    unsigned short* wloD3 = whiD3 + 36864;
    float* imapF = (float*)(sc + 1769472);                // 1MB

    // 0. fused prep: detect + accum zero + weight splits + dep NHWC + imap
    prep_all_kernel<<<4800, 256, 0, stream>>>((const unsigned*)cur_x,
        up_w, conv2_w, d1_w, d2_w, d3_w, dep_x, in_map,
        wbase, (unsigned short*)W1, imapF, accum, flag);

    // 1. u1 = conv3x3(dep_x-NHWC; up) -> W0 NHWC [65536][256] ; stats -> a0
    //    512-thr blocks (ROWS=4, WCO=2), MINW=4 (VGPR cap 128, no spill).
    conv3_mfma<128, 256, 64, 64, 4, 2, 2, false, false, false, true, 4, 1, true>
        <<<dim3(256, 4), 512, 0, stream>>>((const void*)W1, whi1, wlo1, up_b,
            nullptr, nullptr, nullptr, nullptr, nullptr, nullptr, W0, flag, a0, 256);
    conv3_mfma<128, 256, 64, 64, 4, 2, 2, false, false, false, true, 4, 0, true>
        <<<dim3(256, 4), 512, 0, stream>>>((const void*)W1, whi1, wlo1, up_b,
            nullptr, nullptr, nullptr, nullptr, nullptr, nullptr, W0, flag, a0, 256);
    // 2. dep = shuffle(relu(bn(u1))) -> W1 NHWC [262144][64]
    shuffle_bn_nhwc_kernel<<<2048, 256, 0, stream>>>(W0, a0, up_g, up_be, W1, flag);
    // 3. t = dep + beta*conv3x3(cur_x * inc) -> W0 (inc computed inline)
    conv3_mfma<64, 64, 128, 128, 4, 2, 1, true, true, false, false, 4, -1, true>
        <<<dim3(1024, 1), 512, 0, stream>>>(cur_x, whi2, wlo2, conv2_b,
            imapF, W1, beta, nullptr, nullptr, nullptr, W0, flag, nullptr, 0);
    // 4. u_d1 = conv(t; d1) -> W1 ; stats -> a1
    conv3_mfma<64, 64, 128, 128, 4, 2, 0, false, false, false, true, 4, -1, true>
        <<<dim3(1024, 1), 512, 0, stream>>>(W0, whiD1, wloD1, d1_b,
            nullptr, nullptr, nullptr, nullptr, nullptr, nullptr, W1, flag, a1, 64);
    // 5. u_d2 = conv(relu(bn1(u_d1)); d2) -> W0 ; stats -> a2
    conv3_mfma<64, 64, 128, 128, 4, 2, 0, false, false, true, true, 4, -1, true>
        <<<dim3(1024, 1), 512, 0, stream>>>(W1, whiD2, wloD2, d2_b,
            nullptr, nullptr, nullptr, a1, d1_g, d1_be, W0, flag, a2, 64);
    // 6. u_d3 = conv(relu(bn2(u_d2)); d3) -> W1 ; stats -> a3
    conv3_mfma<64, 64, 128, 128, 4, 2, 0, false, false, true, true, 4, -1, true>
        <<<dim3(1024, 1), 512, 0, stream>>>(W0, whiD3, wloD3, d3_b,
            nullptr, nullptr, nullptr, a2, d2_g, d2_be, W1, flag, a3, 64);
    // 7. r3 = relu(bn3(u_d3)) -> d_out (+ W0 f32 copy only in bf16 mode)
    bn_out_kernel<<<4096, 256, 0, stream>>>(W1, a3, d3_g, d3_be, W0, d_out, flag);
    // 8. 7x7 conv partials (channel-split x4) -> W1[0:4MB]
    conv7x7_part_kernel<<<dim3(8, 2, 64), 256, 0, stream>>>(W0, d_out, out_w, W1, flag);
    // 9. output_map = sum partials + bias -> d_out + 16.7M
    finalize_out_kernel<<<1024, 256, 0, stream>>>(W1, out_b, d_out, flag);
}